// Round 9
// baseline (850.468 us; speedup 1.0000x reference)
//
#include <hip/hip_runtime.h>
#include <hip/hip_bf16.h>
#include <math.h>

typedef __hip_bfloat16 bf16;
typedef __attribute__((ext_vector_type(8))) short short8;
typedef __attribute__((ext_vector_type(8))) unsigned short ushort8;
typedef __attribute__((ext_vector_type(4))) float floatx4;

#define NNODES 50000
#define NHALF  25000
#define NEDGES 400000
#define NEG_SLOPE 0.2f

__device__ __forceinline__ float b2f(bf16 x){ return __bfloat162float(x); }
__device__ __forceinline__ bf16  f2b(float x){ return __float2bfloat16(x); }
__device__ __forceinline__ float u2f(unsigned short u){ return __uint_as_float(((unsigned)u) << 16); }

__device__ __forceinline__ float loadF(const void* p, long i, int f32){
  return f32 ? ((const float*)p)[i] : b2f(((const bf16*)p)[i]);
}
__device__ __forceinline__ void storeOut(void* p, long i, float v, int f32){
  if (f32) ((float*)p)[i] = v; else ((bf16*)p)[i] = f2b(v);
}

// order-preserving float<->uint encoding (for atomicMax over signed floats)
__device__ __forceinline__ unsigned fenc(float f){
  unsigned b = __float_as_uint(f);
  return (b & 0x80000000u) ? ~b : (b | 0x80000000u);
}
__device__ __forceinline__ float fdec(unsigned k){
  unsigned b = (k & 0x80000000u) ? (k & 0x7fffffffu) : ~k;
  return __uint_as_float(b);
}

// async global->LDS, 16B per lane; lds base must be wave-uniform
__device__ __forceinline__ void gl_lds16(const bf16* g, short* l){
  __builtin_amdgcn_global_load_lds(
      (const __attribute__((address_space(1))) unsigned int*)g,
      (__attribute__((address_space(3))) unsigned int*)l, 16, 0, 0);
}

// ---------------- dtype / index-width detection ------------------------------
__global__ void k_detect(const unsigned short* __restrict__ x0u,
                         const unsigned* __restrict__ dstu,
                         int* __restrict__ flags)
{
  __shared__ int sh_insane;
  __shared__ unsigned sh_or;
  if (threadIdx.x == 0) { sh_insane = 0; sh_or = 0u; }
  __syncthreads();
  int insane = 0; unsigned orv = 0u;
  for (int i = threadIdx.x; i < 2048; i += 256) {
    unsigned short w = x0u[2 * i];
    int ex = (w >> 7) & 0xFF;
    if (w != 0 && (ex < 108 || ex > 142)) insane++;
    orv |= dstu[2 * i + 1];
  }
  atomicAdd(&sh_insane, insane);
  atomicOr(&sh_or, orv);
  __syncthreads();
  if (threadIdx.x == 0) {
    flags[0] = (sh_insane > 512) ? 1 : 0;   // fp32 tensors
    flags[1] = (sh_or == 0u) ? 1 : 0;       // int64 indices
  }
}

// index conversion + degree count fused (deg must be pre-zeroed)
__global__ void k_conv_idx(const int* __restrict__ sraw, const int* __restrict__ draw,
                           int* __restrict__ s32, int* __restrict__ d32,
                           int* __restrict__ deg,
                           const int* __restrict__ flags)
{
  int e = blockIdx.x * blockDim.x + threadIdx.x;
  if (e >= NEDGES) return;
  int stride = flags[1] ? 2 : 1;
  int s = sraw[(long)e * stride];
  int d = draw[(long)e * stride];
  s32[e] = s;
  d32[e] = d;
  atomicAdd(&deg[d], 1);
}

// ---------------- weight canonicalization -> bf16, transposed in-place -------
// M==0: linear copy to dst. M>0: src is row-major [K][M]; write dst[m*stride+k]
// (transposed, zero-padded rows handled by a prior memset of the region).
struct WSrc { const void* p[17]; void* dst[17]; int n[17]; int M[17]; int st[17]; };

__global__ void k_canon(WSrc w, const int* __restrict__ flags, int total)
{
  int f32 = flags[0];
  for (int t = blockIdx.x * blockDim.x + threadIdx.x; t < total;
       t += gridDim.x * blockDim.x) {
    int idx = t, k = 0;
    while (idx >= w.n[k]) { idx -= w.n[k]; k++; }
    bf16 v = f2b(loadF(w.p[k], idx, f32));
    if (w.M[k] == 0) {
      ((bf16*)w.dst[k])[idx] = v;
    } else {
      int m = idx % w.M[k], kk = idx / w.M[k];
      ((bf16*)w.dst[k])[(long)m * w.st[k] + kk] = v;
    }
  }
}

// ---------------- x -> contiguous bf16 [50000,256], 8 elems/thread -----------
__global__ void k_convx(const void* __restrict__ x0, const void* __restrict__ x1,
                        bf16* __restrict__ xb, const int* __restrict__ flags)
{
  long t = (long)(blockIdx.x * blockDim.x + threadIdx.x) * 8;
  if (t >= (long)NNODES * 256) return;
  long half = (long)NHALF * 256;
  const void* src = (t < half) ? x0 : x1;
  long off = (t < half) ? t : t - half;
  short8 o;
  if (flags[0]) {
    const float* f = (const float*)src + off;
    floatx4 a = *(const floatx4*)f;
    floatx4 b = *(const floatx4*)(f + 4);
    #pragma unroll
    for (int j = 0; j < 4; ++j) {
      bf16 x = f2b(a[j]); o[j] = *(short*)&x;
      bf16 y = f2b(b[j]); o[j + 4] = *(short*)&y;
    }
  } else {
    o = *(const short8*)((const bf16*)src + off);
  }
  *(short8*)(xb + t) = o;
}

// ---------------- MFMA GEMM: C[N,ldc] = A[N,K] @ Wt^T ------------------------
// Optional fused attention-logit epilogue (elOut != nullptr, requires ldc=512,
// 128-col y-tiles => each y-tile covers exactly heads {colBase/64, +1}):
// el[n,h] = sum_d ft[n,h*64+d]*al[h,d] computed from fp32 acc fragments,
// plus per-head global max -> atomicMax into Menc[h] (el) / Menc[8+h] (er).
__global__ __launch_bounds__(256) void k_gemm_mfma(
    const bf16* __restrict__ A, const bf16* __restrict__ Wt,
    bf16* __restrict__ C, int N, int K, int ldc, int Mout,
    const bf16* __restrict__ bias,
    const bf16* __restrict__ al, const bf16* __restrict__ ar,
    float* __restrict__ elOut, float* __restrict__ erOut,
    unsigned* __restrict__ Menc)
{
  __shared__ __align__(16) short lsA[128 * 32];
  __shared__ __align__(16) short lsB[128 * 32];
  int tid = threadIdx.x;
  int wave = tid >> 6, lane = tid & 63;
  int wm = wave >> 1, wn = wave & 1;
  int rowBase = blockIdx.x * 128;
  int colBase = blockIdx.y * 128;

  floatx4 acc[4][4] = {};
  int laneRow = lane >> 2;
  int laneCol = (lane & 3) * 8;
  int cA0 = wave * 2, cA1 = cA0 + 1;

  for (int kb = 0; kb < K; kb += 32) {
    int r0 = rowBase + cA0 * 16 + laneRow; if (r0 > N - 1) r0 = N - 1;
    int r1 = rowBase + cA1 * 16 + laneRow; if (r1 > N - 1) r1 = N - 1;
    gl_lds16(A + (size_t)r0 * K + kb + laneCol, &lsA[cA0 * 512]);
    gl_lds16(A + (size_t)r1 * K + kb + laneCol, &lsA[cA1 * 512]);
    int m0 = colBase + cA0 * 16 + laneRow;
    int m1 = colBase + cA1 * 16 + laneRow;
    gl_lds16(Wt + (size_t)m0 * K + kb + laneCol, &lsB[cA0 * 512]);
    gl_lds16(Wt + (size_t)m1 * K + kb + laneCol, &lsB[cA1 * 512]);
    __syncthreads();

    short8 af[4], bfr[4];
    int lr = lane & 15, q8 = (lane >> 4) * 8;
    #pragma unroll
    for (int mt = 0; mt < 4; ++mt)
      af[mt] = *(const short8*)&lsA[(wm * 64 + mt * 16 + lr) * 32 + q8];
    #pragma unroll
    for (int nt = 0; nt < 4; ++nt)
      bfr[nt] = *(const short8*)&lsB[(wn * 64 + nt * 16 + lr) * 32 + q8];
    #pragma unroll
    for (int mt = 0; mt < 4; ++mt)
      #pragma unroll
      for (int nt = 0; nt < 4; ++nt)
        acc[mt][nt] = __builtin_amdgcn_mfma_f32_16x16x32_bf16(
            af[mt], bfr[nt], acc[mt][nt], 0, 0, 0);
    __syncthreads();
  }

  int lc = lane & 15, rq = (lane >> 4) * 4;
  #pragma unroll
  for (int mt = 0; mt < 4; ++mt) {
    #pragma unroll
    for (int nt = 0; nt < 4; ++nt) {
      int col = colBase + wn * 64 + nt * 16 + lc;
      if (col >= Mout) continue;
      float bsv = bias ? b2f(bias[col]) : 0.f;
      #pragma unroll
      for (int r = 0; r < 4; ++r) {
        int row = rowBase + wm * 64 + mt * 16 + rq + r;
        if (row < N) C[(size_t)row * ldc + col] = f2b(acc[mt][nt][r] + bsv);
      }
    }
  }

  // ---- fused el/er + per-head global-max epilogue ----
  if (elOut) {
    int h = (colBase >> 6) + wn;           // head owned by this wave
    float alv[4], arv[4];
    #pragma unroll
    for (int nt = 0; nt < 4; ++nt) {
      alv[nt] = b2f(al[h * 64 + nt * 16 + lc]);
      arv[nt] = b2f(ar[h * 64 + nt * 16 + lc]);
    }
    float mael = -1e30f, maer = -1e30f;
    #pragma unroll
    for (int mt = 0; mt < 4; ++mt) {
      #pragma unroll
      for (int r = 0; r < 4; ++r) {
        float pe = acc[mt][0][r] * alv[0] + acc[mt][1][r] * alv[1]
                 + acc[mt][2][r] * alv[2] + acc[mt][3][r] * alv[3];
        float pr = acc[mt][0][r] * arv[0] + acc[mt][1][r] * arv[1]
                 + acc[mt][2][r] * arv[2] + acc[mt][3][r] * arv[3];
        #pragma unroll
        for (int off = 1; off < 16; off <<= 1) {
          pe += __shfl_xor(pe, off);
          pr += __shfl_xor(pr, off);
        }
        int row = rowBase + wm * 64 + mt * 16 + rq + r;
        if (row < N) {
          if (lc == 0) { elOut[row * 8 + h] = pe; erOut[row * 8 + h] = pr; }
          mael = fmaxf(mael, pe);
          maer = fmaxf(maer, pr);
        }
      }
    }
    // lanes within a 16-group hold identical values; combine across rq groups
    #pragma unroll
    for (int off = 16; off < 64; off <<= 1) {
      mael = fmaxf(mael, __shfl_xor(mael, off));
      maer = fmaxf(maer, __shfl_xor(maer, off));
    }
    if (lane == 0) {
      atomicMax(&Menc[h], fenc(mael));
      atomicMax(&Menc[8 + h], fenc(maer));
    }
  }
}

// ---------------- attention logits (H=1, D=16, ft2 [N,32]) -------------------
__global__ __launch_bounds__(256) void k_elr1(
    const bf16* __restrict__ ft2,
    const bf16* __restrict__ al, const bf16* __restrict__ ar,
    float* __restrict__ el, float* __restrict__ er,
    unsigned* __restrict__ Menc)
{
  __shared__ float rA[4], rB[4];
  int tid = threadIdx.x;
  int n = blockIdx.x * 256 + tid;
  float a = -1e30f, b = -1e30f;
  if (n < NNODES) {
    const unsigned short* f = (const unsigned short*)ft2 + (size_t)n * 32;
    float aa = 0.f, bb = 0.f;
    #pragma unroll
    for (int d = 0; d < 16; ++d) {
      float x = u2f(f[d]);
      aa += x * b2f(al[d]);
      bb += x * b2f(ar[d]);
    }
    a = aa; b = bb;
    el[n] = a; er[n] = b;
  }
  #pragma unroll
  for (int off = 1; off <= 32; off <<= 1) {
    a = fmaxf(a, __shfl_xor(a, off));
    b = fmaxf(b, __shfl_xor(b, off));
  }
  int wave = tid >> 6, lane = tid & 63;
  if (lane == 0) { rA[wave] = a; rB[wave] = b; }
  __syncthreads();
  if (tid == 0) {
    float ma = -1e30f, mb = -1e30f;
    #pragma unroll
    for (int w2 = 0; w2 < 4; ++w2) { ma = fmaxf(ma, rA[w2]); mb = fmaxf(mb, rB[w2]); }
    atomicMax(&Menc[0], fenc(ma));
    atomicMax(&Menc[1], fenc(mb));
  }
}

// ---------------- CSR build: 3-stage parallel exclusive scan -----------------
__global__ __launch_bounds__(1024) void k_bsum(const int* __restrict__ deg,
                                               int* __restrict__ bsum, int n)
{
  __shared__ int ws[16];
  int tid = threadIdx.x, lane = tid & 63, wv = tid >> 6;
  int i = blockIdx.x * 1024 + tid;
  int v = (i < n) ? deg[i] : 0;
  #pragma unroll
  for (int off = 1; off < 64; off <<= 1) v += __shfl_xor(v, off);
  if (lane == 0) ws[wv] = v;
  __syncthreads();
  if (tid < 16) {
    int s = ws[tid];
    #pragma unroll
    for (int off = 1; off < 16; off <<= 1) s += __shfl_xor(s, off);
    if (tid == 0) bsum[blockIdx.x] = s;
  }
}

__global__ void k_bscan(int* __restrict__ bsum, int* __restrict__ row_start,
                        int nb, int n)
{
  int lane = threadIdx.x;
  int v = (lane < nb) ? bsum[lane] : 0;
  int x = v;
  #pragma unroll
  for (int off = 1; off < 64; off <<= 1) {
    int y = __shfl_up(x, off);
    if (lane >= off) x += y;
  }
  if (lane < nb) bsum[lane] = x - v;       // exclusive block offsets
  if (lane == 63) row_start[n] = x;        // grand total
}

// stage C: per-block exclusive scan + block offset -> row_start AND cursor
__global__ __launch_bounds__(1024) void k_scan2(const int* __restrict__ deg,
                                                const int* __restrict__ boff,
                                                int* __restrict__ row_start,
                                                int* __restrict__ cursor, int n)
{
  __shared__ int ws[16];
  int tid = threadIdx.x, lane = tid & 63, wv = tid >> 6;
  int i = blockIdx.x * 1024 + tid;
  int v = (i < n) ? deg[i] : 0;
  int x = v;
  #pragma unroll
  for (int off = 1; off < 64; off <<= 1) {
    int y = __shfl_up(x, off);
    if (lane >= off) x += y;
  }
  if (lane == 63) ws[wv] = x;
  __syncthreads();
  if (wv == 0 && lane < 16) {
    int s = ws[lane];
    int xs = s;
    #pragma unroll
    for (int off = 1; off < 16; off <<= 1) {
      int y = __shfl_up(xs, off);
      if (lane >= off) xs += y;
    }
    ws[lane] = xs - s;                     // exclusive wave offsets
  }
  __syncthreads();
  if (i < n) {
    int val = boff[blockIdx.x] + ws[wv] + x - v;
    row_start[i] = val;
    cursor[i] = val;
  }
}

__global__ void k_fill(const int* __restrict__ src, const int* __restrict__ dst,
                       int* __restrict__ cursor, int* __restrict__ csr_src, int E)
{
  int e = blockIdx.x * blockDim.x + threadIdx.x;
  if (e < E) {
    int p = atomicAdd(&cursor[dst[e]], 1);
    csr_src[p] = src[e];
  }
}

// ---------------- fused aggregation, H=8 D=64 --------------------------------
// SINGLE CSR pass, inline softmax numerator with global per-head bound
// (decoded from Menc: [0..7]=el-max, [8..15]=er-max, encoded uints).
// One wave per node; lane owns dims [lane*8,+8); head group g = lane>>3.
// mode 0: elu(agg + bias)      mode 1: elu(agg + hin + bias), hout may alias hin
__global__ __launch_bounds__(256) void k_agg8(
    const int* __restrict__ row_start, const int* __restrict__ csr_src,
    const float* __restrict__ el, const float* __restrict__ er,
    const unsigned* __restrict__ Menc,
    const bf16* __restrict__ ft, const bf16* __restrict__ hin,
    const bf16* __restrict__ bias,
    bf16* __restrict__ hout, void* __restrict__ dout, long dout_off,
    const int* __restrict__ flags, int mode)
{
  int wv = (int)((blockIdx.x * blockDim.x + threadIdx.x) >> 6);
  int lane = threadIdx.x & 63;
  if (wv >= NNODES) return;
  int n = wv, g = lane >> 3;
  int st = row_start[n], en = row_start[n + 1];
  float mm = fdec(Menc[g]) + fdec(Menc[8 + g]);
  float Mh = mm > 0.f ? mm : NEG_SLOPE * mm;
  float ern = er[n * 8 + g];

  const unsigned short* ftS = (const unsigned short*)ft;
  float ssum = 0.f;
  float acc[8] = {};
  int i = st;
  for (; i + 4 <= en; i += 4) {
    int sn0 = csr_src[i],     sn1 = csr_src[i + 1];
    int sn2 = csr_src[i + 2], sn3 = csr_src[i + 3];
    float e0 = el[sn0 * 8 + g], e1 = el[sn1 * 8 + g];
    float e2 = el[sn2 * 8 + g], e3 = el[sn3 * 8 + g];
    ushort8 r0 = *(const ushort8*)&ftS[(size_t)sn0 * 512 + lane * 8];
    ushort8 r1 = *(const ushort8*)&ftS[(size_t)sn1 * 512 + lane * 8];
    ushort8 r2 = *(const ushort8*)&ftS[(size_t)sn2 * 512 + lane * 8];
    ushort8 r3 = *(const ushort8*)&ftS[(size_t)sn3 * 512 + lane * 8];
    float v0 = e0 + ern, v1 = e1 + ern, v2 = e2 + ern, v3 = e3 + ern;
    v0 = v0 > 0.f ? v0 : NEG_SLOPE * v0;
    v1 = v1 > 0.f ? v1 : NEG_SLOPE * v1;
    v2 = v2 > 0.f ? v2 : NEG_SLOPE * v2;
    v3 = v3 > 0.f ? v3 : NEG_SLOPE * v3;
    float w0 = __expf(v0 - Mh), w1 = __expf(v1 - Mh);
    float w2 = __expf(v2 - Mh), w3 = __expf(v3 - Mh);
    ssum += (w0 + w1) + (w2 + w3);
    #pragma unroll
    for (int j = 0; j < 8; ++j)
      acc[j] += (w0 * u2f(r0[j]) + w1 * u2f(r1[j]))
              + (w2 * u2f(r2[j]) + w3 * u2f(r3[j]));
  }
  for (; i < en; ++i) {
    int sn = csr_src[i];
    float v0 = el[sn * 8 + g] + ern;
    v0 = v0 > 0.f ? v0 : NEG_SLOPE * v0;
    float w0 = __expf(v0 - Mh);
    ushort8 r0 = *(const ushort8*)&ftS[(size_t)sn * 512 + lane * 8];
    ssum += w0;
    #pragma unroll
    for (int j = 0; j < 8; ++j)
      acc[j] += w0 * u2f(r0[j]);
  }

  float inv = ssum > 0.f ? 1.f / ssum : 0.f;
  int f32 = flags[0];
  short8 outv;
  float rr[8];
  #pragma unroll
  for (int j = 0; j < 8; ++j) {
    int col = lane * 8 + j;
    float r = acc[j] * inv + b2f(bias[col]);
    if (mode == 1) r += b2f(hin[(size_t)n * 512 + col]);
    r = r > 0.f ? r : expm1f(r);
    rr[j] = r;
    bf16 o = f2b(r);
    outv[j] = *(short*)&o;
  }
  *(short8*)&hout[(size_t)n * 512 + lane * 8] = outv;
  if (dout) {
    if (f32) {
      floatx4 o0, o1;
      #pragma unroll
      for (int j = 0; j < 4; ++j) { o0[j] = rr[j]; o1[j] = rr[j + 4]; }
      float* dp = (float*)dout + dout_off + (size_t)n * 512 + lane * 8;
      *(floatx4*)dp = o0;
      *(floatx4*)(dp + 4) = o1;
    } else {
      *(short8*)&((bf16*)dout)[dout_off + (size_t)n * 512 + lane * 8] = outv;
    }
  }
}

// ---------------- fused aggregation, H=1 D=16 (output layer) -----------------
__global__ __launch_bounds__(256) void k_agg1(
    const int* __restrict__ row_start, const int* __restrict__ csr_src,
    const float* __restrict__ el, const float* __restrict__ er,
    const unsigned* __restrict__ Menc,
    const bf16* __restrict__ ft2, const bf16* __restrict__ bias,
    void* __restrict__ dout, const int* __restrict__ flags)
{
  int wv = (int)((blockIdx.x * blockDim.x + threadIdx.x) >> 6);
  int lane = threadIdx.x & 63;
  if (wv >= NNODES) return;
  int n = wv, sub = lane >> 4, d = lane & 15;
  int st = row_start[n], en = row_start[n + 1];
  float mm = fdec(Menc[0]) + fdec(Menc[1]);
  float M0 = mm > 0.f ? mm : NEG_SLOPE * mm;
  float ern = er[n];
  float ssum = 0.f, acc = 0.f;
  for (int i = st + sub; i < en; i += 4) {
    int sn = csr_src[i];
    float v = el[sn] + ern;
    v = v > 0.f ? v : NEG_SLOPE * v;
    float ex = __expf(v - M0);
    acc  += ex * b2f(ft2[(size_t)sn * 32 + d]);
    ssum += ex;
  }
  acc  += __shfl_xor(acc, 16);  acc  += __shfl_xor(acc, 32);
  ssum += __shfl_xor(ssum, 16); ssum += __shfl_xor(ssum, 32);
  if (sub == 0) {
    float inv = ssum > 0.f ? 1.f / ssum : 0.f;
    float r = acc * inv + b2f(bias[d]) + b2f(ft2[(size_t)n * 32 + 16 + d]);
    storeOut(dout, (size_t)n * 16 + d, r, flags[0]);
  }
}

// -----------------------------------------------------------------------------
extern "C" void kernel_launch(void* const* d_in, const int* in_sizes, int n_in,
                              void* d_out, int out_size, void* d_ws, size_t ws_size,
                              hipStream_t stream)
{
  const void* x0   = d_in[0];
  const void* x1   = d_in[1];
  const int*  srcR = (const int*)d_in[2];
  const int*  dstR = (const int*)d_in[3];

  char* p = (char*)d_ws;
  auto alloc = [&](size_t bytes) { char* r = p; p += (bytes + 255) & ~(size_t)255; return r; };
  int*      flags     = (int*)  alloc(256);
  bf16*     wc        = (bf16*) alloc((size_t)347312 * 2);
  int*      src32     = (int*)  alloc((size_t)NEDGES * 4);
  int*      dst32     = (int*)  alloc((size_t)NEDGES * 4);
  bf16*     xb        = (bf16*) alloc((size_t)NNODES * 256 * 2);
  bf16*     h0        = (bf16*) alloc((size_t)NNODES * 64 * 2);
  bf16*     hB        = (bf16*) alloc((size_t)NNODES * 512 * 2);
  bf16*     ft        = (bf16*) alloc((size_t)NNODES * 512 * 2);
  bf16*     ft2       = (bf16*) alloc((size_t)NNODES * 32 * 2);
  float*    el        = (float*)alloc((size_t)NNODES * 8 * 4);
  float*    er        = (float*)alloc((size_t)NNODES * 8 * 4);
  int*      deg       = (int*)  alloc((size_t)NNODES * 4);
  int*      row_start = (int*)  alloc((size_t)(NNODES + 1) * 4);
  int*      cursor    = (int*)  alloc((size_t)NNODES * 4);
  int*      csr_src   = (int*)  alloc((size_t)NEDGES * 4);
  int*      bsum      = (int*)  alloc((size_t)64 * 4);
  unsigned* Menc      = (unsigned*)alloc(256);     // [0..15]=L0, [16..31]=L1, [32..33]=L2
  // transposed weights: contiguous region, zeroed once for pad rows
  bf16*     fc0t      = (bf16*) alloc((size_t)128 * 256 * 2);
  bf16*     fc1t      = (bf16*) alloc((size_t)128 * 256 * 2);
  bf16*     W0t       = (bf16*) alloc((size_t)512 * 64 * 2);
  bf16*     W1t       = (bf16*) alloc((size_t)512 * 512 * 2);
  bf16*     W2c       = (bf16*) alloc((size_t)128 * 512 * 2);
  size_t twBytes = ((size_t)128*256 + 128*256 + 512*64 + 512*512 + 128*512) * 2;

  const int B = 256;
  auto blk = [](long total, int b) { return (unsigned)((total + b - 1) / b); };
  const int NSCB = (NNODES + 1023) / 1024;   // 49 scan blocks

  // ---- memsets (deg for degree count, Menc for atomic max, tw pad rows) ----
  hipMemsetAsync(deg, 0, (size_t)NNODES * 4, stream);
  hipMemsetAsync(Menc, 0, 256, stream);
  hipMemsetAsync(fc0t, 0, twBytes, stream);

  // ---- detect dtypes, convert indices (+degree) ----
  k_detect<<<1, 256, 0, stream>>>((const unsigned short*)x0, (const unsigned*)dstR, flags);
  k_conv_idx<<<blk(NEDGES, B), B, 0, stream>>>(srcR, dstR, src32, dst32, deg, flags);

  // ---- canonicalize weights (direct transposed writes for W tensors) ----
  long woff[18]; woff[0] = 0;
  const int widx[17] = {4,5,6,7, 8,9,10,11, 12,13,14,15, 16,17,18,19, 20};
  const int wn[17]   = {16384,64,16384,64, 32768,512,512,512, 262144,512,512,512,
                        8192,16,16,16, 8192};
  for (int i = 0; i < 17; ++i) woff[i + 1] = woff[i] + wn[i];

  WSrc wsrc;
  int wtotal = 0;
  for (int i = 0; i < 17; ++i) {
    wsrc.p[i] = d_in[widx[i]]; wsrc.n[i] = wn[i];
    wsrc.dst[i] = wc + woff[i]; wsrc.M[i] = 0; wsrc.st[i] = 0;
    wtotal += wn[i];
  }
  // transposed destinations: src row-major [K][M] -> dst[m*st + k]
  wsrc.dst[0]  = fc0t;            wsrc.M[0]  = 64;  wsrc.st[0]  = 256; // fc0W
  wsrc.dst[2]  = fc1t;            wsrc.M[2]  = 64;  wsrc.st[2]  = 256; // fc1W
  wsrc.dst[4]  = W0t;             wsrc.M[4]  = 512; wsrc.st[4]  = 64;  // W0
  wsrc.dst[8]  = W1t;             wsrc.M[8]  = 512; wsrc.st[8]  = 512; // W1
  wsrc.dst[12] = W2c;             wsrc.M[12] = 16;  wsrc.st[12] = 512; // W2
  wsrc.dst[16] = W2c + 16 * 512;  wsrc.M[16] = 16;  wsrc.st[16] = 512; // resW2
  k_canon<<<blk(wtotal, B), B, 0, stream>>>(wsrc, flags, wtotal);
  k_convx<<<blk((long)NNODES * 32, B), B, 0, stream>>>(x0, x1, xb, flags);

  const bf16 *fc0b = wc + woff[1], *fc1b = wc + woff[3];
  const bf16 *al0  = wc + woff[5],  *ar0 = wc + woff[6],  *b0 = wc + woff[7];
  const bf16 *al1  = wc + woff[9],  *ar1 = wc + woff[10], *b1 = wc + woff[11];
  const bf16 *al2  = wc + woff[13], *ar2 = wc + woff[14], *b2 = wc + woff[15];

  // ---- CSR build: parallel scan (A: block sums, B: scan sums, C: scatter) ----
  k_bsum <<<NSCB, 1024, 0, stream>>>(deg, bsum, NNODES);
  k_bscan<<<1, 64, 0, stream>>>(bsum, row_start, NSCB, NNODES);
  k_scan2<<<NSCB, 1024, 0, stream>>>(deg, bsum, row_start, cursor, NNODES);
  k_fill<<<blk(NEDGES, B), B, 0, stream>>>(src32, dst32, cursor, csr_src, NEDGES);

  auto gemm = [&](const bf16* A, const bf16* Wt, bf16* C, int N, int K,
                  int ldc, int Mout, int ytiles, const bf16* bias,
                  const bf16* gal = nullptr, const bf16* gar = nullptr,
                  float* gel = nullptr, float* ger = nullptr,
                  unsigned* gM = nullptr) {
    dim3 g(blk(N, 128), ytiles);
    k_gemm_mfma<<<g, 256, 0, stream>>>(A, Wt, C, N, K, ldc, Mout, bias,
                                       gal, gar, gel, ger, gM);
  };

  // ---- input projections ----
  gemm(xb, fc0t, h0, NHALF, 256, 64, 64, 1, fc0b);
  gemm(xb + (size_t)NHALF * 256, fc1t, h0 + (size_t)NHALF * 64, NHALF, 256, 64, 64, 1, fc1b);

  unsigned aggGrid = blk((long)NNODES * 64, B);
  unsigned nblk1 = blk(NNODES, B);

  // ---- layer 0: 64 -> 8x64, ELU (el/er/max fused into GEMM epilogue) ----
  gemm(h0, W0t, ft, NNODES, 64, 512, 512, 4, nullptr, al0, ar0, el, er, Menc);
  k_agg8<<<aggGrid, B, 0, stream>>>(row_start, csr_src, el, er, Menc, ft, nullptr, b0,
                                    hB, nullptr, 0, flags, 0);

  // ---- layer 1: 512 -> 8x64, identity residual, ELU (+ encoded out) ----
  gemm(hB, W1t, ft, NNODES, 512, 512, 512, 4, nullptr, al1, ar1, el, er, Menc + 16);
  k_agg8<<<aggGrid, B, 0, stream>>>(row_start, csr_src, el, er, Menc + 16, ft, hB, b1,
                                    hB, d_out, (long)NNODES * 16, flags, 1);

  // ---- output layer: 512 -> 1x16 (+ fused resW2 in cols 16..31) ----
  gemm(hB, W2c, ft2, NNODES, 512, 32, 32, 1, nullptr);
  k_elr1<<<nblk1, B, 0, stream>>>(ft2, al2, ar2, el, er, Menc + 32);
  k_agg1<<<aggGrid, B, 0, stream>>>(row_start, csr_src, el, er, Menc + 32, ft2, b2, d_out, flags);
}

// Round 10
// 646.399 us; speedup vs baseline: 1.3157x; 1.3157x over previous
//
#include <hip/hip_runtime.h>
#include <hip/hip_bf16.h>
#include <math.h>

typedef __hip_bfloat16 bf16;
typedef __attribute__((ext_vector_type(8))) short short8;
typedef __attribute__((ext_vector_type(8))) unsigned short ushort8;
typedef __attribute__((ext_vector_type(4))) float floatx4;

#define NNODES 50000
#define NHALF  25000
#define NEDGES 400000
#define NEG_SLOPE 0.2f

__device__ __forceinline__ float b2f(bf16 x){ return __bfloat162float(x); }
__device__ __forceinline__ bf16  f2b(float x){ return __float2bfloat16(x); }
__device__ __forceinline__ float u2f(unsigned short u){ return __uint_as_float(((unsigned)u) << 16); }

__device__ __forceinline__ float loadF(const void* p, long i, int f32){
  return f32 ? ((const float*)p)[i] : b2f(((const bf16*)p)[i]);
}
__device__ __forceinline__ void storeOut(void* p, long i, float v, int f32){
  if (f32) ((float*)p)[i] = v; else ((bf16*)p)[i] = f2b(v);
}

// order-preserving float<->uint encoding (for atomicMax over signed floats)
__device__ __forceinline__ unsigned fenc(float f){
  unsigned b = __float_as_uint(f);
  return (b & 0x80000000u) ? ~b : (b | 0x80000000u);
}
__device__ __forceinline__ float fdec(unsigned k){
  unsigned b = (k & 0x80000000u) ? (k & 0x7fffffffu) : ~k;
  return __uint_as_float(b);
}

// async global->LDS, 16B per lane; lds base must be wave-uniform
__device__ __forceinline__ void gl_lds16(const bf16* g, short* l){
  __builtin_amdgcn_global_load_lds(
      (const __attribute__((address_space(1))) unsigned int*)g,
      (__attribute__((address_space(3))) unsigned int*)l, 16, 0, 0);
}

// ---------------- dtype / index-width detection ------------------------------
__global__ void k_detect(const unsigned short* __restrict__ x0u,
                         const unsigned* __restrict__ dstu,
                         int* __restrict__ flags)
{
  __shared__ int sh_insane;
  __shared__ unsigned sh_or;
  if (threadIdx.x == 0) { sh_insane = 0; sh_or = 0u; }
  __syncthreads();
  int insane = 0; unsigned orv = 0u;
  for (int i = threadIdx.x; i < 2048; i += 256) {
    unsigned short w = x0u[2 * i];
    int ex = (w >> 7) & 0xFF;
    if (w != 0 && (ex < 108 || ex > 142)) insane++;
    orv |= dstu[2 * i + 1];
  }
  atomicAdd(&sh_insane, insane);
  atomicOr(&sh_or, orv);
  __syncthreads();
  if (threadIdx.x == 0) {
    flags[0] = (sh_insane > 512) ? 1 : 0;   // fp32 tensors
    flags[1] = (sh_or == 0u) ? 1 : 0;       // int64 indices
  }
}

// index conversion + degree count fused (deg must be pre-zeroed)
__global__ void k_conv_idx(const int* __restrict__ sraw, const int* __restrict__ draw,
                           int* __restrict__ s32, int* __restrict__ d32,
                           int* __restrict__ deg,
                           const int* __restrict__ flags)
{
  int e = blockIdx.x * blockDim.x + threadIdx.x;
  if (e >= NEDGES) return;
  int stride = flags[1] ? 2 : 1;
  int s = sraw[(long)e * stride];
  int d = draw[(long)e * stride];
  s32[e] = s;
  d32[e] = d;
  atomicAdd(&deg[d], 1);
}

// ---------------- weight canonicalization -> bf16, transposed in-place -------
// M==0: linear copy to dst. M>0: src is row-major [K][M]; write dst[m*stride+k]
// (transposed, zero-padded rows handled by a prior memset of the region).
struct WSrc { const void* p[17]; void* dst[17]; int n[17]; int M[17]; int st[17]; };

__global__ void k_canon(WSrc w, const int* __restrict__ flags, int total)
{
  int f32 = flags[0];
  for (int t = blockIdx.x * blockDim.x + threadIdx.x; t < total;
       t += gridDim.x * blockDim.x) {
    int idx = t, k = 0;
    while (idx >= w.n[k]) { idx -= w.n[k]; k++; }
    bf16 v = f2b(loadF(w.p[k], idx, f32));
    if (w.M[k] == 0) {
      ((bf16*)w.dst[k])[idx] = v;
    } else {
      int m = idx % w.M[k], kk = idx / w.M[k];
      ((bf16*)w.dst[k])[(long)m * w.st[k] + kk] = v;
    }
  }
}

// ---------------- x -> contiguous bf16 [50000,256], 8 elems/thread -----------
__global__ void k_convx(const void* __restrict__ x0, const void* __restrict__ x1,
                        bf16* __restrict__ xb, const int* __restrict__ flags)
{
  long t = (long)(blockIdx.x * blockDim.x + threadIdx.x) * 8;
  if (t >= (long)NNODES * 256) return;
  long half = (long)NHALF * 256;
  const void* src = (t < half) ? x0 : x1;
  long off = (t < half) ? t : t - half;
  short8 o;
  if (flags[0]) {
    const float* f = (const float*)src + off;
    floatx4 a = *(const floatx4*)f;
    floatx4 b = *(const floatx4*)(f + 4);
    #pragma unroll
    for (int j = 0; j < 4; ++j) {
      bf16 x = f2b(a[j]); o[j] = *(short*)&x;
      bf16 y = f2b(b[j]); o[j + 4] = *(short*)&y;
    }
  } else {
    o = *(const short8*)((const bf16*)src + off);
  }
  *(short8*)(xb + t) = o;
}

// ---------------- MFMA GEMM: C[N,ldc] = A[N,K] @ Wt^T ------------------------
// Optional fused attention-logit epilogue (elOut != nullptr, requires ldc=512,
// 128-col y-tiles => each y-tile covers exactly heads {colBase/64, +1}):
// el[n,h] = sum_d ft[n,h*64+d]*al[h,d] computed from fp32 acc fragments.
// Per-head global max: wave max -> LDS atomicMax (2 heads/block) -> ONE
// 2-lane vector atomic per block into Menc (round-9's per-wave device atomics
// serialized on one cache line: 25K scalar atomics ~= 200us; now ~3K).
__global__ __launch_bounds__(256) void k_gemm_mfma(
    const bf16* __restrict__ A, const bf16* __restrict__ Wt,
    bf16* __restrict__ C, int N, int K, int ldc, int Mout,
    const bf16* __restrict__ bias,
    const bf16* __restrict__ al, const bf16* __restrict__ ar,
    float* __restrict__ elOut, float* __restrict__ erOut,
    unsigned* __restrict__ Menc)
{
  __shared__ __align__(16) short lsA[128 * 32];
  __shared__ __align__(16) short lsB[128 * 32];
  __shared__ unsigned sMaxE[2], sMaxR[2];
  int tid = threadIdx.x;
  int wave = tid >> 6, lane = tid & 63;
  int wm = wave >> 1, wn = wave & 1;
  int rowBase = blockIdx.x * 128;
  int colBase = blockIdx.y * 128;

  if (tid < 2) { sMaxE[tid] = 0u; sMaxR[tid] = 0u; }  // ordered by loop barrier

  floatx4 acc[4][4] = {};
  int laneRow = lane >> 2;
  int laneCol = (lane & 3) * 8;
  int cA0 = wave * 2, cA1 = cA0 + 1;

  for (int kb = 0; kb < K; kb += 32) {
    int r0 = rowBase + cA0 * 16 + laneRow; if (r0 > N - 1) r0 = N - 1;
    int r1 = rowBase + cA1 * 16 + laneRow; if (r1 > N - 1) r1 = N - 1;
    gl_lds16(A + (size_t)r0 * K + kb + laneCol, &lsA[cA0 * 512]);
    gl_lds16(A + (size_t)r1 * K + kb + laneCol, &lsA[cA1 * 512]);
    int m0 = colBase + cA0 * 16 + laneRow;
    int m1 = colBase + cA1 * 16 + laneRow;
    gl_lds16(Wt + (size_t)m0 * K + kb + laneCol, &lsB[cA0 * 512]);
    gl_lds16(Wt + (size_t)m1 * K + kb + laneCol, &lsB[cA1 * 512]);
    __syncthreads();

    short8 af[4], bfr[4];
    int lr = lane & 15, q8 = (lane >> 4) * 8;
    #pragma unroll
    for (int mt = 0; mt < 4; ++mt)
      af[mt] = *(const short8*)&lsA[(wm * 64 + mt * 16 + lr) * 32 + q8];
    #pragma unroll
    for (int nt = 0; nt < 4; ++nt)
      bfr[nt] = *(const short8*)&lsB[(wn * 64 + nt * 16 + lr) * 32 + q8];
    #pragma unroll
    for (int mt = 0; mt < 4; ++mt)
      #pragma unroll
      for (int nt = 0; nt < 4; ++nt)
        acc[mt][nt] = __builtin_amdgcn_mfma_f32_16x16x32_bf16(
            af[mt], bfr[nt], acc[mt][nt], 0, 0, 0);
    __syncthreads();
  }

  int lc = lane & 15, rq = (lane >> 4) * 4;
  #pragma unroll
  for (int mt = 0; mt < 4; ++mt) {
    #pragma unroll
    for (int nt = 0; nt < 4; ++nt) {
      int col = colBase + wn * 64 + nt * 16 + lc;
      if (col >= Mout) continue;
      float bsv = bias ? b2f(bias[col]) : 0.f;
      #pragma unroll
      for (int r = 0; r < 4; ++r) {
        int row = rowBase + wm * 64 + mt * 16 + rq + r;
        if (row < N) C[(size_t)row * ldc + col] = f2b(acc[mt][nt][r] + bsv);
      }
    }
  }

  // ---- fused el/er + per-head global-max epilogue ----
  if (elOut) {
    int h = (colBase >> 6) + wn;           // head owned by this wave
    float alv[4], arv[4];
    #pragma unroll
    for (int nt = 0; nt < 4; ++nt) {
      alv[nt] = b2f(al[h * 64 + nt * 16 + lc]);
      arv[nt] = b2f(ar[h * 64 + nt * 16 + lc]);
    }
    float mael = -1e30f, maer = -1e30f;
    #pragma unroll
    for (int mt = 0; mt < 4; ++mt) {
      #pragma unroll
      for (int r = 0; r < 4; ++r) {
        float pe = acc[mt][0][r] * alv[0] + acc[mt][1][r] * alv[1]
                 + acc[mt][2][r] * alv[2] + acc[mt][3][r] * alv[3];
        float pr = acc[mt][0][r] * arv[0] + acc[mt][1][r] * arv[1]
                 + acc[mt][2][r] * arv[2] + acc[mt][3][r] * arv[3];
        #pragma unroll
        for (int off = 1; off < 16; off <<= 1) {
          pe += __shfl_xor(pe, off);
          pr += __shfl_xor(pr, off);
        }
        int row = rowBase + wm * 64 + mt * 16 + rq + r;
        if (row < N) {
          if (lc == 0) { elOut[row * 8 + h] = pe; erOut[row * 8 + h] = pr; }
          mael = fmaxf(mael, pe);
          maer = fmaxf(maer, pr);
        }
      }
    }
    // lanes within a 16-group hold identical values; combine across rq groups
    #pragma unroll
    for (int off = 16; off < 64; off <<= 1) {
      mael = fmaxf(mael, __shfl_xor(mael, off));
      maer = fmaxf(maer, __shfl_xor(maer, off));
    }
    if (lane == 0) {
      atomicMax(&sMaxE[wn], fenc(mael));   // LDS atomics: cheap
      atomicMax(&sMaxR[wn], fenc(maer));
    }
    __syncthreads();
    if (tid < 2) {                          // one 2-lane vector atomic pair/block
      int h0 = colBase >> 6;
      atomicMax(&Menc[h0 + tid], sMaxE[tid]);
      atomicMax(&Menc[8 + h0 + tid], sMaxR[tid]);
    }
  }
}

// ---------------- attention logits (H=1, D=16, ft2 [N,32]) -------------------
__global__ __launch_bounds__(256) void k_elr1(
    const bf16* __restrict__ ft2,
    const bf16* __restrict__ al, const bf16* __restrict__ ar,
    float* __restrict__ el, float* __restrict__ er,
    unsigned* __restrict__ Menc)
{
  __shared__ float rA[4], rB[4];
  int tid = threadIdx.x;
  int n = blockIdx.x * 256 + tid;
  float a = -1e30f, b = -1e30f;
  if (n < NNODES) {
    const unsigned short* f = (const unsigned short*)ft2 + (size_t)n * 32;
    float aa = 0.f, bb = 0.f;
    #pragma unroll
    for (int d = 0; d < 16; ++d) {
      float x = u2f(f[d]);
      aa += x * b2f(al[d]);
      bb += x * b2f(ar[d]);
    }
    a = aa; b = bb;
    el[n] = a; er[n] = b;
  }
  #pragma unroll
  for (int off = 1; off <= 32; off <<= 1) {
    a = fmaxf(a, __shfl_xor(a, off));
    b = fmaxf(b, __shfl_xor(b, off));
  }
  int wave = tid >> 6, lane = tid & 63;
  if (lane == 0) { rA[wave] = a; rB[wave] = b; }
  __syncthreads();
  if (tid == 0) {
    float ma = -1e30f, mb = -1e30f;
    #pragma unroll
    for (int w2 = 0; w2 < 4; ++w2) { ma = fmaxf(ma, rA[w2]); mb = fmaxf(mb, rB[w2]); }
    atomicMax(&Menc[0], fenc(ma));
    atomicMax(&Menc[1], fenc(mb));
  }
}

// ---------------- CSR build: 3-stage parallel exclusive scan -----------------
__global__ __launch_bounds__(1024) void k_bsum(const int* __restrict__ deg,
                                               int* __restrict__ bsum, int n)
{
  __shared__ int ws[16];
  int tid = threadIdx.x, lane = tid & 63, wv = tid >> 6;
  int i = blockIdx.x * 1024 + tid;
  int v = (i < n) ? deg[i] : 0;
  #pragma unroll
  for (int off = 1; off < 64; off <<= 1) v += __shfl_xor(v, off);
  if (lane == 0) ws[wv] = v;
  __syncthreads();
  if (tid < 16) {
    int s = ws[tid];
    #pragma unroll
    for (int off = 1; off < 16; off <<= 1) s += __shfl_xor(s, off);
    if (tid == 0) bsum[blockIdx.x] = s;
  }
}

__global__ void k_bscan(int* __restrict__ bsum, int* __restrict__ row_start,
                        int nb, int n)
{
  int lane = threadIdx.x;
  int v = (lane < nb) ? bsum[lane] : 0;
  int x = v;
  #pragma unroll
  for (int off = 1; off < 64; off <<= 1) {
    int y = __shfl_up(x, off);
    if (lane >= off) x += y;
  }
  if (lane < nb) bsum[lane] = x - v;       // exclusive block offsets
  if (lane == 63) row_start[n] = x;        // grand total
}

// stage C: per-block exclusive scan + block offset -> row_start AND cursor
__global__ __launch_bounds__(1024) void k_scan2(const int* __restrict__ deg,
                                                const int* __restrict__ boff,
                                                int* __restrict__ row_start,
                                                int* __restrict__ cursor, int n)
{
  __shared__ int ws[16];
  int tid = threadIdx.x, lane = tid & 63, wv = tid >> 6;
  int i = blockIdx.x * 1024 + tid;
  int v = (i < n) ? deg[i] : 0;
  int x = v;
  #pragma unroll
  for (int off = 1; off < 64; off <<= 1) {
    int y = __shfl_up(x, off);
    if (lane >= off) x += y;
  }
  if (lane == 63) ws[wv] = x;
  __syncthreads();
  if (wv == 0 && lane < 16) {
    int s = ws[lane];
    int xs = s;
    #pragma unroll
    for (int off = 1; off < 16; off <<= 1) {
      int y = __shfl_up(xs, off);
      if (lane >= off) xs += y;
    }
    ws[lane] = xs - s;                     // exclusive wave offsets
  }
  __syncthreads();
  if (i < n) {
    int val = boff[blockIdx.x] + ws[wv] + x - v;
    row_start[i] = val;
    cursor[i] = val;
  }
}

__global__ void k_fill(const int* __restrict__ src, const int* __restrict__ dst,
                       int* __restrict__ cursor, int* __restrict__ csr_src, int E)
{
  int e = blockIdx.x * blockDim.x + threadIdx.x;
  if (e < E) {
    int p = atomicAdd(&cursor[dst[e]], 1);
    csr_src[p] = src[e];
  }
}

// ---------------- fused aggregation, H=8 D=64 --------------------------------
// SINGLE CSR pass, inline softmax numerator with global per-head bound
// (decoded from Menc: [0..7]=el-max, [8..15]=er-max, encoded uints).
// One wave per node; lane owns dims [lane*8,+8); head group g = lane>>3.
// mode 0: elu(agg + bias)      mode 1: elu(agg + hin + bias), hout may alias hin
__global__ __launch_bounds__(256) void k_agg8(
    const int* __restrict__ row_start, const int* __restrict__ csr_src,
    const float* __restrict__ el, const float* __restrict__ er,
    const unsigned* __restrict__ Menc,
    const bf16* __restrict__ ft, const bf16* __restrict__ hin,
    const bf16* __restrict__ bias,
    bf16* __restrict__ hout, void* __restrict__ dout, long dout_off,
    const int* __restrict__ flags, int mode)
{
  int wv = (int)((blockIdx.x * blockDim.x + threadIdx.x) >> 6);
  int lane = threadIdx.x & 63;
  if (wv >= NNODES) return;
  int n = wv, g = lane >> 3;
  int st = row_start[n], en = row_start[n + 1];
  float mm = fdec(Menc[g]) + fdec(Menc[8 + g]);
  float Mh = mm > 0.f ? mm : NEG_SLOPE * mm;
  float ern = er[n * 8 + g];

  const unsigned short* ftS = (const unsigned short*)ft;
  float ssum = 0.f;
  float acc[8] = {};
  int i = st;
  for (; i + 4 <= en; i += 4) {
    int sn0 = csr_src[i],     sn1 = csr_src[i + 1];
    int sn2 = csr_src[i + 2], sn3 = csr_src[i + 3];
    float e0 = el[sn0 * 8 + g], e1 = el[sn1 * 8 + g];
    float e2 = el[sn2 * 8 + g], e3 = el[sn3 * 8 + g];
    ushort8 r0 = *(const ushort8*)&ftS[(size_t)sn0 * 512 + lane * 8];
    ushort8 r1 = *(const ushort8*)&ftS[(size_t)sn1 * 512 + lane * 8];
    ushort8 r2 = *(const ushort8*)&ftS[(size_t)sn2 * 512 + lane * 8];
    ushort8 r3 = *(const ushort8*)&ftS[(size_t)sn3 * 512 + lane * 8];
    float v0 = e0 + ern, v1 = e1 + ern, v2 = e2 + ern, v3 = e3 + ern;
    v0 = v0 > 0.f ? v0 : NEG_SLOPE * v0;
    v1 = v1 > 0.f ? v1 : NEG_SLOPE * v1;
    v2 = v2 > 0.f ? v2 : NEG_SLOPE * v2;
    v3 = v3 > 0.f ? v3 : NEG_SLOPE * v3;
    float w0 = __expf(v0 - Mh), w1 = __expf(v1 - Mh);
    float w2 = __expf(v2 - Mh), w3 = __expf(v3 - Mh);
    ssum += (w0 + w1) + (w2 + w3);
    #pragma unroll
    for (int j = 0; j < 8; ++j)
      acc[j] += (w0 * u2f(r0[j]) + w1 * u2f(r1[j]))
              + (w2 * u2f(r2[j]) + w3 * u2f(r3[j]));
  }
  for (; i < en; ++i) {
    int sn = csr_src[i];
    float v0 = el[sn * 8 + g] + ern;
    v0 = v0 > 0.f ? v0 : NEG_SLOPE * v0;
    float w0 = __expf(v0 - Mh);
    ushort8 r0 = *(const ushort8*)&ftS[(size_t)sn * 512 + lane * 8];
    ssum += w0;
    #pragma unroll
    for (int j = 0; j < 8; ++j)
      acc[j] += w0 * u2f(r0[j]);
  }

  float inv = ssum > 0.f ? 1.f / ssum : 0.f;
  int f32 = flags[0];
  short8 outv;
  float rr[8];
  #pragma unroll
  for (int j = 0; j < 8; ++j) {
    int col = lane * 8 + j;
    float r = acc[j] * inv + b2f(bias[col]);
    if (mode == 1) r += b2f(hin[(size_t)n * 512 + col]);
    r = r > 0.f ? r : expm1f(r);
    rr[j] = r;
    bf16 o = f2b(r);
    outv[j] = *(short*)&o;
  }
  *(short8*)&hout[(size_t)n * 512 + lane * 8] = outv;
  if (dout) {
    if (f32) {
      floatx4 o0, o1;
      #pragma unroll
      for (int j = 0; j < 4; ++j) { o0[j] = rr[j]; o1[j] = rr[j + 4]; }
      float* dp = (float*)dout + dout_off + (size_t)n * 512 + lane * 8;
      *(floatx4*)dp = o0;
      *(floatx4*)(dp + 4) = o1;
    } else {
      *(short8*)&((bf16*)dout)[dout_off + (size_t)n * 512 + lane * 8] = outv;
    }
  }
}

// ---------------- fused aggregation, H=1 D=16 (output layer) -----------------
__global__ __launch_bounds__(256) void k_agg1(
    const int* __restrict__ row_start, const int* __restrict__ csr_src,
    const float* __restrict__ el, const float* __restrict__ er,
    const unsigned* __restrict__ Menc,
    const bf16* __restrict__ ft2, const bf16* __restrict__ bias,
    void* __restrict__ dout, const int* __restrict__ flags)
{
  int wv = (int)((blockIdx.x * blockDim.x + threadIdx.x) >> 6);
  int lane = threadIdx.x & 63;
  if (wv >= NNODES) return;
  int n = wv, sub = lane >> 4, d = lane & 15;
  int st = row_start[n], en = row_start[n + 1];
  float mm = fdec(Menc[0]) + fdec(Menc[1]);
  float M0 = mm > 0.f ? mm : NEG_SLOPE * mm;
  float ern = er[n];
  float ssum = 0.f, acc = 0.f;
  for (int i = st + sub; i < en; i += 4) {
    int sn = csr_src[i];
    float v = el[sn] + ern;
    v = v > 0.f ? v : NEG_SLOPE * v;
    float ex = __expf(v - M0);
    acc  += ex * b2f(ft2[(size_t)sn * 32 + d]);
    ssum += ex;
  }
  acc  += __shfl_xor(acc, 16);  acc  += __shfl_xor(acc, 32);
  ssum += __shfl_xor(ssum, 16); ssum += __shfl_xor(ssum, 32);
  if (sub == 0) {
    float inv = ssum > 0.f ? 1.f / ssum : 0.f;
    float r = acc * inv + b2f(bias[d]) + b2f(ft2[(size_t)n * 32 + 16 + d]);
    storeOut(dout, (size_t)n * 16 + d, r, flags[0]);
  }
}

// -----------------------------------------------------------------------------
extern "C" void kernel_launch(void* const* d_in, const int* in_sizes, int n_in,
                              void* d_out, int out_size, void* d_ws, size_t ws_size,
                              hipStream_t stream)
{
  const void* x0   = d_in[0];
  const void* x1   = d_in[1];
  const int*  srcR = (const int*)d_in[2];
  const int*  dstR = (const int*)d_in[3];

  char* p = (char*)d_ws;
  auto alloc = [&](size_t bytes) { char* r = p; p += (bytes + 255) & ~(size_t)255; return r; };
  int*      flags     = (int*)  alloc(256);
  bf16*     wc        = (bf16*) alloc((size_t)347312 * 2);
  int*      src32     = (int*)  alloc((size_t)NEDGES * 4);
  int*      dst32     = (int*)  alloc((size_t)NEDGES * 4);
  bf16*     xb        = (bf16*) alloc((size_t)NNODES * 256 * 2);
  bf16*     h0        = (bf16*) alloc((size_t)NNODES * 64 * 2);
  bf16*     hB        = (bf16*) alloc((size_t)NNODES * 512 * 2);
  bf16*     ft        = (bf16*) alloc((size_t)NNODES * 512 * 2);
  bf16*     ft2       = (bf16*) alloc((size_t)NNODES * 32 * 2);
  float*    el        = (float*)alloc((size_t)NNODES * 8 * 4);
  float*    er        = (float*)alloc((size_t)NNODES * 8 * 4);
  int*      deg       = (int*)  alloc((size_t)NNODES * 4);
  int*      row_start = (int*)  alloc((size_t)(NNODES + 1) * 4);
  int*      cursor    = (int*)  alloc((size_t)NNODES * 4);
  int*      csr_src   = (int*)  alloc((size_t)NEDGES * 4);
  int*      bsum      = (int*)  alloc((size_t)64 * 4);
  unsigned* Menc      = (unsigned*)alloc(256);     // [0..15]=L0, [16..31]=L1, [32..33]=L2
  // transposed weights: contiguous region, zeroed once for pad rows
  bf16*     fc0t      = (bf16*) alloc((size_t)128 * 256 * 2);
  bf16*     fc1t      = (bf16*) alloc((size_t)128 * 256 * 2);
  bf16*     W0t       = (bf16*) alloc((size_t)512 * 64 * 2);
  bf16*     W1t       = (bf16*) alloc((size_t)512 * 512 * 2);
  bf16*     W2c       = (bf16*) alloc((size_t)128 * 512 * 2);
  size_t twBytes = ((size_t)128*256 + 128*256 + 512*64 + 512*512 + 128*512) * 2;

  const int B = 256;
  auto blk = [](long total, int b) { return (unsigned)((total + b - 1) / b); };
  const int NSCB = (NNODES + 1023) / 1024;   // 49 scan blocks

  // ---- memsets (deg for degree count, Menc for atomic max, tw pad rows) ----
  hipMemsetAsync(deg, 0, (size_t)NNODES * 4, stream);
  hipMemsetAsync(Menc, 0, 256, stream);
  hipMemsetAsync(fc0t, 0, twBytes, stream);

  // ---- detect dtypes, convert indices (+degree) ----
  k_detect<<<1, 256, 0, stream>>>((const unsigned short*)x0, (const unsigned*)dstR, flags);
  k_conv_idx<<<blk(NEDGES, B), B, 0, stream>>>(srcR, dstR, src32, dst32, deg, flags);

  // ---- canonicalize weights (direct transposed writes for W tensors) ----
  long woff[18]; woff[0] = 0;
  const int widx[17] = {4,5,6,7, 8,9,10,11, 12,13,14,15, 16,17,18,19, 20};
  const int wn[17]   = {16384,64,16384,64, 32768,512,512,512, 262144,512,512,512,
                        8192,16,16,16, 8192};
  for (int i = 0; i < 17; ++i) woff[i + 1] = woff[i] + wn[i];

  WSrc wsrc;
  int wtotal = 0;
  for (int i = 0; i < 17; ++i) {
    wsrc.p[i] = d_in[widx[i]]; wsrc.n[i] = wn[i];
    wsrc.dst[i] = wc + woff[i]; wsrc.M[i] = 0; wsrc.st[i] = 0;
    wtotal += wn[i];
  }
  // transposed destinations: src row-major [K][M] -> dst[m*st + k]
  wsrc.dst[0]  = fc0t;            wsrc.M[0]  = 64;  wsrc.st[0]  = 256; // fc0W
  wsrc.dst[2]  = fc1t;            wsrc.M[2]  = 64;  wsrc.st[2]  = 256; // fc1W
  wsrc.dst[4]  = W0t;             wsrc.M[4]  = 512; wsrc.st[4]  = 64;  // W0
  wsrc.dst[8]  = W1t;             wsrc.M[8]  = 512; wsrc.st[8]  = 512; // W1
  wsrc.dst[12] = W2c;             wsrc.M[12] = 16;  wsrc.st[12] = 512; // W2
  wsrc.dst[16] = W2c + 16 * 512;  wsrc.M[16] = 16;  wsrc.st[16] = 512; // resW2
  k_canon<<<blk(wtotal, B), B, 0, stream>>>(wsrc, flags, wtotal);
  k_convx<<<blk((long)NNODES * 32, B), B, 0, stream>>>(x0, x1, xb, flags);

  const bf16 *fc0b = wc + woff[1], *fc1b = wc + woff[3];
  const bf16 *al0  = wc + woff[5],  *ar0 = wc + woff[6],  *b0 = wc + woff[7];
  const bf16 *al1  = wc + woff[9],  *ar1 = wc + woff[10], *b1 = wc + woff[11];
  const bf16 *al2  = wc + woff[13], *ar2 = wc + woff[14], *b2 = wc + woff[15];

  // ---- CSR build: parallel scan (A: block sums, B: scan sums, C: scatter) ----
  k_bsum <<<NSCB, 1024, 0, stream>>>(deg, bsum, NNODES);
  k_bscan<<<1, 64, 0, stream>>>(bsum, row_start, NSCB, NNODES);
  k_scan2<<<NSCB, 1024, 0, stream>>>(deg, bsum, row_start, cursor, NNODES);
  k_fill<<<blk(NEDGES, B), B, 0, stream>>>(src32, dst32, cursor, csr_src, NEDGES);

  auto gemm = [&](const bf16* A, const bf16* Wt, bf16* C, int N, int K,
                  int ldc, int Mout, int ytiles, const bf16* bias,
                  const bf16* gal = nullptr, const bf16* gar = nullptr,
                  float* gel = nullptr, float* ger = nullptr,
                  unsigned* gM = nullptr) {
    dim3 g(blk(N, 128), ytiles);
    k_gemm_mfma<<<g, 256, 0, stream>>>(A, Wt, C, N, K, ldc, Mout, bias,
                                       gal, gar, gel, ger, gM);
  };

  // ---- input projections ----
  gemm(xb, fc0t, h0, NHALF, 256, 64, 64, 1, fc0b);
  gemm(xb + (size_t)NHALF * 256, fc1t, h0 + (size_t)NHALF * 64, NHALF, 256, 64, 64, 1, fc1b);

  unsigned aggGrid = blk((long)NNODES * 64, B);
  unsigned nblk1 = blk(NNODES, B);

  // ---- layer 0: 64 -> 8x64, ELU (el/er/max fused into GEMM epilogue) ----
  gemm(h0, W0t, ft, NNODES, 64, 512, 512, 4, nullptr, al0, ar0, el, er, Menc);
  k_agg8<<<aggGrid, B, 0, stream>>>(row_start, csr_src, el, er, Menc, ft, nullptr, b0,
                                    hB, nullptr, 0, flags, 0);

  // ---- layer 1: 512 -> 8x64, identity residual, ELU (+ encoded out) ----
  gemm(hB, W1t, ft, NNODES, 512, 512, 512, 4, nullptr, al1, ar1, el, er, Menc + 16);
  k_agg8<<<aggGrid, B, 0, stream>>>(row_start, csr_src, el, er, Menc + 16, ft, hB, b1,
                                    hB, d_out, (long)NNODES * 16, flags, 1);

  // ---- output layer: 512 -> 1x16 (+ fused resW2 in cols 16..31) ----
  gemm(hB, W2c, ft2, NNODES, 512, 32, 32, 1, nullptr);
  k_elr1<<<nblk1, B, 0, stream>>>(ft2, al2, ar2, el, er, Menc + 32);
  k_agg1<<<aggGrid, B, 0, stream>>>(row_start, csr_src, el, er, Menc + 32, ft2, b2, d_out, flags);
}

// Round 11
// 640.685 us; speedup vs baseline: 1.3274x; 1.0089x over previous
//
#include <hip/hip_runtime.h>
#include <hip/hip_bf16.h>
#include <math.h>

typedef __hip_bfloat16 bf16;
typedef __attribute__((ext_vector_type(8))) short short8;
typedef __attribute__((ext_vector_type(8))) unsigned short ushort8;
typedef __attribute__((ext_vector_type(4))) float floatx4;

#define NNODES 50000
#define NHALF  25000
#define NEDGES 400000
#define NEG_SLOPE 0.2f

__device__ __forceinline__ float b2f(bf16 x){ return __bfloat162float(x); }
__device__ __forceinline__ bf16  f2b(float x){ return __float2bfloat16(x); }
__device__ __forceinline__ float u2f(unsigned short u){ return __uint_as_float(((unsigned)u) << 16); }

__device__ __forceinline__ float loadF(const void* p, long i, int f32){
  return f32 ? ((const float*)p)[i] : b2f(((const bf16*)p)[i]);
}
__device__ __forceinline__ void storeOut(void* p, long i, float v, int f32){
  if (f32) ((float*)p)[i] = v; else ((bf16*)p)[i] = f2b(v);
}

// order-preserving float<->uint encoding (for atomicMax over signed floats)
__device__ __forceinline__ unsigned fenc(float f){
  unsigned b = __float_as_uint(f);
  return (b & 0x80000000u) ? ~b : (b | 0x80000000u);
}
__device__ __forceinline__ float fdec(unsigned k){
  unsigned b = (k & 0x80000000u) ? (k & 0x7fffffffu) : ~k;
  return __uint_as_float(b);
}

// async global->LDS, 16B per lane; lds base must be wave-uniform
__device__ __forceinline__ void gl_lds16(const bf16* g, short* l){
  __builtin_amdgcn_global_load_lds(
      (const __attribute__((address_space(1))) unsigned int*)g,
      (__attribute__((address_space(3))) unsigned int*)l, 16, 0, 0);
}

// ---------------- dtype / index-width detection ------------------------------
__global__ void k_detect(const unsigned short* __restrict__ x0u,
                         const unsigned* __restrict__ dstu,
                         int* __restrict__ flags)
{
  __shared__ int sh_insane;
  __shared__ unsigned sh_or;
  if (threadIdx.x == 0) { sh_insane = 0; sh_or = 0u; }
  __syncthreads();
  int insane = 0; unsigned orv = 0u;
  for (int i = threadIdx.x; i < 2048; i += 256) {
    unsigned short w = x0u[2 * i];
    int ex = (w >> 7) & 0xFF;
    if (w != 0 && (ex < 108 || ex > 142)) insane++;
    orv |= dstu[2 * i + 1];
  }
  atomicAdd(&sh_insane, insane);
  atomicOr(&sh_or, orv);
  __syncthreads();
  if (threadIdx.x == 0) {
    flags[0] = (sh_insane > 512) ? 1 : 0;   // fp32 tensors
    flags[1] = (sh_or == 0u) ? 1 : 0;       // int64 indices
  }
}

// index conversion + degree count fused (deg must be pre-zeroed)
__global__ void k_conv_idx(const int* __restrict__ sraw, const int* __restrict__ draw,
                           int* __restrict__ s32, int* __restrict__ d32,
                           int* __restrict__ deg,
                           const int* __restrict__ flags)
{
  int e = blockIdx.x * blockDim.x + threadIdx.x;
  if (e >= NEDGES) return;
  int stride = flags[1] ? 2 : 1;
  int s = sraw[(long)e * stride];
  int d = draw[(long)e * stride];
  s32[e] = s;
  d32[e] = d;
  atomicAdd(&deg[d], 1);
}

// ---------------- weight canonicalization -> bf16, transposed in-place -------
// M==0: linear copy to dst. M>0: src is row-major [K][M]; write dst[m*stride+k]
// (transposed, zero-padded rows handled by a prior memset of the region).
struct WSrc { const void* p[17]; void* dst[17]; int n[17]; int M[17]; int st[17]; };

__global__ void k_canon(WSrc w, const int* __restrict__ flags, int total)
{
  int f32 = flags[0];
  for (int t = blockIdx.x * blockDim.x + threadIdx.x; t < total;
       t += gridDim.x * blockDim.x) {
    int idx = t, k = 0;
    while (idx >= w.n[k]) { idx -= w.n[k]; k++; }
    bf16 v = f2b(loadF(w.p[k], idx, f32));
    if (w.M[k] == 0) {
      ((bf16*)w.dst[k])[idx] = v;
    } else {
      int m = idx % w.M[k], kk = idx / w.M[k];
      ((bf16*)w.dst[k])[(long)m * w.st[k] + kk] = v;
    }
  }
}

// ---------------- x -> contiguous bf16 [50000,256], 8 elems/thread -----------
__global__ void k_convx(const void* __restrict__ x0, const void* __restrict__ x1,
                        bf16* __restrict__ xb, const int* __restrict__ flags)
{
  long t = (long)(blockIdx.x * blockDim.x + threadIdx.x) * 8;
  if (t >= (long)NNODES * 256) return;
  long half = (long)NHALF * 256;
  const void* src = (t < half) ? x0 : x1;
  long off = (t < half) ? t : t - half;
  short8 o;
  if (flags[0]) {
    const float* f = (const float*)src + off;
    floatx4 a = *(const floatx4*)f;
    floatx4 b = *(const floatx4*)(f + 4);
    #pragma unroll
    for (int j = 0; j < 4; ++j) {
      bf16 x = f2b(a[j]); o[j] = *(short*)&x;
      bf16 y = f2b(b[j]); o[j + 4] = *(short*)&y;
    }
  } else {
    o = *(const short8*)((const bf16*)src + off);
  }
  *(short8*)(xb + t) = o;
}

// ---------------- MFMA GEMM: C[N,ldc] = A[N,K] @ Wt^T ------------------------
// Optional fused attention-logit epilogue (elOut != nullptr, requires ldc=512,
// 128-col y-tiles => each y-tile covers exactly heads {colBase/64, +1}):
// el[n,h] = sum_d ft[n,h*64+d]*al[h,d] computed from fp32 acc fragments.
// Per-head global max: wave max -> LDS atomicMax (2 heads/block) -> ONE
// 2-lane vector atomic per block into Menc.
__global__ __launch_bounds__(256) void k_gemm_mfma(
    const bf16* __restrict__ A, const bf16* __restrict__ Wt,
    bf16* __restrict__ C, int N, int K, int ldc, int Mout,
    const bf16* __restrict__ bias,
    const bf16* __restrict__ al, const bf16* __restrict__ ar,
    float* __restrict__ elOut, float* __restrict__ erOut,
    unsigned* __restrict__ Menc)
{
  __shared__ __align__(16) short lsA[128 * 32];
  __shared__ __align__(16) short lsB[128 * 32];
  __shared__ unsigned sMaxE[2], sMaxR[2];
  int tid = threadIdx.x;
  int wave = tid >> 6, lane = tid & 63;
  int wm = wave >> 1, wn = wave & 1;
  int rowBase = blockIdx.x * 128;
  int colBase = blockIdx.y * 128;

  if (tid < 2) { sMaxE[tid] = 0u; sMaxR[tid] = 0u; }  // ordered by loop barrier

  floatx4 acc[4][4] = {};
  int laneRow = lane >> 2;
  int laneCol = (lane & 3) * 8;
  int cA0 = wave * 2, cA1 = cA0 + 1;

  for (int kb = 0; kb < K; kb += 32) {
    int r0 = rowBase + cA0 * 16 + laneRow; if (r0 > N - 1) r0 = N - 1;
    int r1 = rowBase + cA1 * 16 + laneRow; if (r1 > N - 1) r1 = N - 1;
    gl_lds16(A + (size_t)r0 * K + kb + laneCol, &lsA[cA0 * 512]);
    gl_lds16(A + (size_t)r1 * K + kb + laneCol, &lsA[cA1 * 512]);
    int m0 = colBase + cA0 * 16 + laneRow;
    int m1 = colBase + cA1 * 16 + laneRow;
    gl_lds16(Wt + (size_t)m0 * K + kb + laneCol, &lsB[cA0 * 512]);
    gl_lds16(Wt + (size_t)m1 * K + kb + laneCol, &lsB[cA1 * 512]);
    __syncthreads();

    short8 af[4], bfr[4];
    int lr = lane & 15, q8 = (lane >> 4) * 8;
    #pragma unroll
    for (int mt = 0; mt < 4; ++mt)
      af[mt] = *(const short8*)&lsA[(wm * 64 + mt * 16 + lr) * 32 + q8];
    #pragma unroll
    for (int nt = 0; nt < 4; ++nt)
      bfr[nt] = *(const short8*)&lsB[(wn * 64 + nt * 16 + lr) * 32 + q8];
    #pragma unroll
    for (int mt = 0; mt < 4; ++mt)
      #pragma unroll
      for (int nt = 0; nt < 4; ++nt)
        acc[mt][nt] = __builtin_amdgcn_mfma_f32_16x16x32_bf16(
            af[mt], bfr[nt], acc[mt][nt], 0, 0, 0);
    __syncthreads();
  }

  int lc = lane & 15, rq = (lane >> 4) * 4;
  #pragma unroll
  for (int mt = 0; mt < 4; ++mt) {
    #pragma unroll
    for (int nt = 0; nt < 4; ++nt) {
      int col = colBase + wn * 64 + nt * 16 + lc;
      if (col >= Mout) continue;
      float bsv = bias ? b2f(bias[col]) : 0.f;
      #pragma unroll
      for (int r = 0; r < 4; ++r) {
        int row = rowBase + wm * 64 + mt * 16 + rq + r;
        if (row < N) C[(size_t)row * ldc + col] = f2b(acc[mt][nt][r] + bsv);
      }
    }
  }

  // ---- fused el/er + per-head global-max epilogue ----
  if (elOut) {
    int h = (colBase >> 6) + wn;           // head owned by this wave
    float alv[4], arv[4];
    #pragma unroll
    for (int nt = 0; nt < 4; ++nt) {
      alv[nt] = b2f(al[h * 64 + nt * 16 + lc]);
      arv[nt] = b2f(ar[h * 64 + nt * 16 + lc]);
    }
    float mael = -1e30f, maer = -1e30f;
    #pragma unroll
    for (int mt = 0; mt < 4; ++mt) {
      #pragma unroll
      for (int r = 0; r < 4; ++r) {
        float pe = acc[mt][0][r] * alv[0] + acc[mt][1][r] * alv[1]
                 + acc[mt][2][r] * alv[2] + acc[mt][3][r] * alv[3];
        float pr = acc[mt][0][r] * arv[0] + acc[mt][1][r] * arv[1]
                 + acc[mt][2][r] * arv[2] + acc[mt][3][r] * arv[3];
        #pragma unroll
        for (int off = 1; off < 16; off <<= 1) {
          pe += __shfl_xor(pe, off);
          pr += __shfl_xor(pr, off);
        }
        int row = rowBase + wm * 64 + mt * 16 + rq + r;
        if (row < N) {
          if (lc == 0) { elOut[row * 8 + h] = pe; erOut[row * 8 + h] = pr; }
          mael = fmaxf(mael, pe);
          maer = fmaxf(maer, pr);
        }
      }
    }
    // lanes within a 16-group hold identical values; combine across rq groups
    #pragma unroll
    for (int off = 16; off < 64; off <<= 1) {
      mael = fmaxf(mael, __shfl_xor(mael, off));
      maer = fmaxf(maer, __shfl_xor(maer, off));
    }
    if (lane == 0) {
      atomicMax(&sMaxE[wn], fenc(mael));   // LDS atomics: cheap
      atomicMax(&sMaxR[wn], fenc(maer));
    }
    __syncthreads();
    if (tid < 2) {                          // one 2-lane vector atomic pair/block
      int h0 = colBase >> 6;
      atomicMax(&Menc[h0 + tid], sMaxE[tid]);
      atomicMax(&Menc[8 + h0 + tid], sMaxR[tid]);
    }
  }
}

// ---------------- attention logits (H=1, D=16, ft2 [N,32]) -------------------
__global__ __launch_bounds__(256) void k_elr1(
    const bf16* __restrict__ ft2,
    const bf16* __restrict__ al, const bf16* __restrict__ ar,
    float* __restrict__ el, float* __restrict__ er,
    unsigned* __restrict__ Menc)
{
  __shared__ float rA[4], rB[4];
  int tid = threadIdx.x;
  int n = blockIdx.x * 256 + tid;
  float a = -1e30f, b = -1e30f;
  if (n < NNODES) {
    const unsigned short* f = (const unsigned short*)ft2 + (size_t)n * 32;
    float aa = 0.f, bb = 0.f;
    #pragma unroll
    for (int d = 0; d < 16; ++d) {
      float x = u2f(f[d]);
      aa += x * b2f(al[d]);
      bb += x * b2f(ar[d]);
    }
    a = aa; b = bb;
    el[n] = a; er[n] = b;
  }
  #pragma unroll
  for (int off = 1; off <= 32; off <<= 1) {
    a = fmaxf(a, __shfl_xor(a, off));
    b = fmaxf(b, __shfl_xor(b, off));
  }
  int wave = tid >> 6, lane = tid & 63;
  if (lane == 0) { rA[wave] = a; rB[wave] = b; }
  __syncthreads();
  if (tid == 0) {
    float ma = -1e30f, mb = -1e30f;
    #pragma unroll
    for (int w2 = 0; w2 < 4; ++w2) { ma = fmaxf(ma, rA[w2]); mb = fmaxf(mb, rB[w2]); }
    atomicMax(&Menc[0], fenc(ma));
    atomicMax(&Menc[1], fenc(mb));
  }
}

// ---------------- CSR build: 3-stage parallel exclusive scan -----------------
__global__ __launch_bounds__(1024) void k_bsum(const int* __restrict__ deg,
                                               int* __restrict__ bsum, int n)
{
  __shared__ int ws[16];
  int tid = threadIdx.x, lane = tid & 63, wv = tid >> 6;
  int i = blockIdx.x * 1024 + tid;
  int v = (i < n) ? deg[i] : 0;
  #pragma unroll
  for (int off = 1; off < 64; off <<= 1) v += __shfl_xor(v, off);
  if (lane == 0) ws[wv] = v;
  __syncthreads();
  if (tid < 16) {
    int s = ws[tid];
    #pragma unroll
    for (int off = 1; off < 16; off <<= 1) s += __shfl_xor(s, off);
    if (tid == 0) bsum[blockIdx.x] = s;
  }
}

__global__ void k_bscan(int* __restrict__ bsum, int* __restrict__ row_start,
                        int nb, int n)
{
  int lane = threadIdx.x;
  int v = (lane < nb) ? bsum[lane] : 0;
  int x = v;
  #pragma unroll
  for (int off = 1; off < 64; off <<= 1) {
    int y = __shfl_up(x, off);
    if (lane >= off) x += y;
  }
  if (lane < nb) bsum[lane] = x - v;       // exclusive block offsets
  if (lane == 63) row_start[n] = x;        // grand total
}

// stage C: per-block exclusive scan + block offset -> row_start AND cursor
__global__ __launch_bounds__(1024) void k_scan2(const int* __restrict__ deg,
                                                const int* __restrict__ boff,
                                                int* __restrict__ row_start,
                                                int* __restrict__ cursor, int n)
{
  __shared__ int ws[16];
  int tid = threadIdx.x, lane = tid & 63, wv = tid >> 6;
  int i = blockIdx.x * 1024 + tid;
  int v = (i < n) ? deg[i] : 0;
  int x = v;
  #pragma unroll
  for (int off = 1; off < 64; off <<= 1) {
    int y = __shfl_up(x, off);
    if (lane >= off) x += y;
  }
  if (lane == 63) ws[wv] = x;
  __syncthreads();
  if (wv == 0 && lane < 16) {
    int s = ws[lane];
    int xs = s;
    #pragma unroll
    for (int off = 1; off < 16; off <<= 1) {
      int y = __shfl_up(xs, off);
      if (lane >= off) xs += y;
    }
    ws[lane] = xs - s;                     // exclusive wave offsets
  }
  __syncthreads();
  if (i < n) {
    int val = boff[blockIdx.x] + ws[wv] + x - v;
    row_start[i] = val;
    cursor[i] = val;
  }
}

__global__ void k_fill(const int* __restrict__ src, const int* __restrict__ dst,
                       int* __restrict__ cursor, int* __restrict__ csr_src, int E)
{
  int e = blockIdx.x * blockDim.x + threadIdx.x;
  if (e < E) {
    int p = atomicAdd(&cursor[dst[e]], 1);
    csr_src[p] = src[e];
  }
}

// ---------------- fused aggregation, H=8 D=64 --------------------------------
// SINGLE CSR pass, inline softmax numerator with global per-head bound
// (decoded from Menc: [0..7]=el-max, [8..15]=er-max, encoded uints).
// One wave per node; lane owns dims [lane*8,+8); head group g = lane>>3.
// dout written NON-TEMPORAL: encoded output (102MB f32) is never re-read;
// cached writes evicted ft (51MB) from L3 (write 150 + ft 51 + hin 51 + misc
// ~= 256MB L3), causing 137MB of ft re-fetch from HBM (FETCH 239 vs ~110 ideal).
// mode 0: elu(agg + bias)      mode 1: elu(agg + hin + bias), hout may alias hin
__global__ __launch_bounds__(256) void k_agg8(
    const int* __restrict__ row_start, const int* __restrict__ csr_src,
    const float* __restrict__ el, const float* __restrict__ er,
    const unsigned* __restrict__ Menc,
    const bf16* __restrict__ ft, const bf16* __restrict__ hin,
    const bf16* __restrict__ bias,
    bf16* __restrict__ hout, void* __restrict__ dout, long dout_off,
    const int* __restrict__ flags, int mode)
{
  int wv = (int)((blockIdx.x * blockDim.x + threadIdx.x) >> 6);
  int lane = threadIdx.x & 63;
  if (wv >= NNODES) return;
  int n = wv, g = lane >> 3;
  int st = row_start[n], en = row_start[n + 1];
  float mm = fdec(Menc[g]) + fdec(Menc[8 + g]);
  float Mh = mm > 0.f ? mm : NEG_SLOPE * mm;
  float ern = er[n * 8 + g];

  const unsigned short* ftS = (const unsigned short*)ft;
  float ssum = 0.f;
  float acc[8] = {};
  int i = st;
  for (; i + 4 <= en; i += 4) {
    int sn0 = csr_src[i],     sn1 = csr_src[i + 1];
    int sn2 = csr_src[i + 2], sn3 = csr_src[i + 3];
    float e0 = el[sn0 * 8 + g], e1 = el[sn1 * 8 + g];
    float e2 = el[sn2 * 8 + g], e3 = el[sn3 * 8 + g];
    ushort8 r0 = *(const ushort8*)&ftS[(size_t)sn0 * 512 + lane * 8];
    ushort8 r1 = *(const ushort8*)&ftS[(size_t)sn1 * 512 + lane * 8];
    ushort8 r2 = *(const ushort8*)&ftS[(size_t)sn2 * 512 + lane * 8];
    ushort8 r3 = *(const ushort8*)&ftS[(size_t)sn3 * 512 + lane * 8];
    float v0 = e0 + ern, v1 = e1 + ern, v2 = e2 + ern, v3 = e3 + ern;
    v0 = v0 > 0.f ? v0 : NEG_SLOPE * v0;
    v1 = v1 > 0.f ? v1 : NEG_SLOPE * v1;
    v2 = v2 > 0.f ? v2 : NEG_SLOPE * v2;
    v3 = v3 > 0.f ? v3 : NEG_SLOPE * v3;
    float w0 = __expf(v0 - Mh), w1 = __expf(v1 - Mh);
    float w2 = __expf(v2 - Mh), w3 = __expf(v3 - Mh);
    ssum += (w0 + w1) + (w2 + w3);
    #pragma unroll
    for (int j = 0; j < 8; ++j)
      acc[j] += (w0 * u2f(r0[j]) + w1 * u2f(r1[j]))
              + (w2 * u2f(r2[j]) + w3 * u2f(r3[j]));
  }
  for (; i < en; ++i) {
    int sn = csr_src[i];
    float v0 = el[sn * 8 + g] + ern;
    v0 = v0 > 0.f ? v0 : NEG_SLOPE * v0;
    float w0 = __expf(v0 - Mh);
    ushort8 r0 = *(const ushort8*)&ftS[(size_t)sn * 512 + lane * 8];
    ssum += w0;
    #pragma unroll
    for (int j = 0; j < 8; ++j)
      acc[j] += w0 * u2f(r0[j]);
  }

  float inv = ssum > 0.f ? 1.f / ssum : 0.f;
  int f32 = flags[0];
  short8 outv;
  float rr[8];
  #pragma unroll
  for (int j = 0; j < 8; ++j) {
    int col = lane * 8 + j;
    float r = acc[j] * inv + b2f(bias[col]);
    if (mode == 1) r += b2f(hin[(size_t)n * 512 + col]);
    r = r > 0.f ? r : expm1f(r);
    rr[j] = r;
    bf16 o = f2b(r);
    outv[j] = *(short*)&o;
  }
  *(short8*)&hout[(size_t)n * 512 + lane * 8] = outv;   // re-read by next GEMM: cached
  if (dout) {
    if (f32) {
      floatx4 o0, o1;
      #pragma unroll
      for (int j = 0; j < 4; ++j) { o0[j] = rr[j]; o1[j] = rr[j + 4]; }
      float* dp = (float*)dout + dout_off + (size_t)n * 512 + lane * 8;
      __builtin_nontemporal_store(o0, (floatx4*)dp);
      __builtin_nontemporal_store(o1, (floatx4*)(dp + 4));
    } else {
      __builtin_nontemporal_store(outv,
          (short8*)&((bf16*)dout)[dout_off + (size_t)n * 512 + lane * 8]);
    }
  }
}

// ---------------- fused aggregation, H=1 D=16 (output layer) -----------------
__global__ __launch_bounds__(256) void k_agg1(
    const int* __restrict__ row_start, const int* __restrict__ csr_src,
    const float* __restrict__ el, const float* __restrict__ er,
    const unsigned* __restrict__ Menc,
    const bf16* __restrict__ ft2, const bf16* __restrict__ bias,
    void* __restrict__ dout, const int* __restrict__ flags)
{
  int wv = (int)((blockIdx.x * blockDim.x + threadIdx.x) >> 6);
  int lane = threadIdx.x & 63;
  if (wv >= NNODES) return;
  int n = wv, sub = lane >> 4, d = lane & 15;
  int st = row_start[n], en = row_start[n + 1];
  float mm = fdec(Menc[0]) + fdec(Menc[1]);
  float M0 = mm > 0.f ? mm : NEG_SLOPE * mm;
  float ern = er[n];
  float ssum = 0.f, acc = 0.f;
  for (int i = st + sub; i < en; i += 4) {
    int sn = csr_src[i];
    float v = el[sn] + ern;
    v = v > 0.f ? v : NEG_SLOPE * v;
    float ex = __expf(v - M0);
    acc  += ex * b2f(ft2[(size_t)sn * 32 + d]);
    ssum += ex;
  }
  acc  += __shfl_xor(acc, 16);  acc  += __shfl_xor(acc, 32);
  ssum += __shfl_xor(ssum, 16); ssum += __shfl_xor(ssum, 32);
  if (sub == 0) {
    float inv = ssum > 0.f ? 1.f / ssum : 0.f;
    float r = acc * inv + b2f(bias[d]) + b2f(ft2[(size_t)n * 32 + 16 + d]);
    if (flags[0]) __builtin_nontemporal_store(r, (float*)dout + (size_t)n * 16 + d);
    else { bf16 o = f2b(r); __builtin_nontemporal_store(*(short*)&o,
             (short*)dout + (size_t)n * 16 + d); }
  }
}

// -----------------------------------------------------------------------------
extern "C" void kernel_launch(void* const* d_in, const int* in_sizes, int n_in,
                              void* d_out, int out_size, void* d_ws, size_t ws_size,
                              hipStream_t stream)
{
  const void* x0   = d_in[0];
  const void* x1   = d_in[1];
  const int*  srcR = (const int*)d_in[2];
  const int*  dstR = (const int*)d_in[3];

  char* p = (char*)d_ws;
  auto alloc = [&](size_t bytes) { char* r = p; p += (bytes + 255) & ~(size_t)255; return r; };
  int*      flags     = (int*)  alloc(256);
  bf16*     wc        = (bf16*) alloc((size_t)347312 * 2);
  int*      src32     = (int*)  alloc((size_t)NEDGES * 4);
  int*      dst32     = (int*)  alloc((size_t)NEDGES * 4);
  bf16*     xb        = (bf16*) alloc((size_t)NNODES * 256 * 2);
  bf16*     h0        = (bf16*) alloc((size_t)NNODES * 64 * 2);
  bf16*     hB        = (bf16*) alloc((size_t)NNODES * 512 * 2);
  bf16*     ft        = (bf16*) alloc((size_t)NNODES * 512 * 2);
  bf16*     ft2       = (bf16*) alloc((size_t)NNODES * 32 * 2);
  float*    el        = (float*)alloc((size_t)NNODES * 8 * 4);
  float*    er        = (float*)alloc((size_t)NNODES * 8 * 4);
  int*      deg       = (int*)  alloc((size_t)NNODES * 4);
  int*      row_start = (int*)  alloc((size_t)(NNODES + 1) * 4);
  int*      cursor    = (int*)  alloc((size_t)NNODES * 4);
  int*      csr_src   = (int*)  alloc((size_t)NEDGES * 4);
  int*      bsum      = (int*)  alloc((size_t)64 * 4);
  unsigned* Menc      = (unsigned*)alloc(256);     // [0..15]=L0, [16..31]=L1, [32..33]=L2
  // transposed weights: contiguous region, zeroed once for pad rows
  bf16*     fc0t      = (bf16*) alloc((size_t)128 * 256 * 2);
  bf16*     fc1t      = (bf16*) alloc((size_t)128 * 256 * 2);
  bf16*     W0t       = (bf16*) alloc((size_t)512 * 64 * 2);
  bf16*     W1t       = (bf16*) alloc((size_t)512 * 512 * 2);
  bf16*     W2c       = (bf16*) alloc((size_t)128 * 512 * 2);
  size_t twBytes = ((size_t)128*256 + 128*256 + 512*64 + 512*512 + 128*512) * 2;

  const int B = 256;
  auto blk = [](long total, int b) { return (unsigned)((total + b - 1) / b); };
  const int NSCB = (NNODES + 1023) / 1024;   // 49 scan blocks

  // ---- memsets (deg for degree count, Menc for atomic max, tw pad rows) ----
  hipMemsetAsync(deg, 0, (size_t)NNODES * 4, stream);
  hipMemsetAsync(Menc, 0, 256, stream);
  hipMemsetAsync(fc0t, 0, twBytes, stream);

  // ---- detect dtypes, convert indices (+degree) ----
  k_detect<<<1, 256, 0, stream>>>((const unsigned short*)x0, (const unsigned*)dstR, flags);
  k_conv_idx<<<blk(NEDGES, B), B, 0, stream>>>(srcR, dstR, src32, dst32, deg, flags);

  // ---- canonicalize weights (direct transposed writes for W tensors) ----
  long woff[18]; woff[0] = 0;
  const int widx[17] = {4,5,6,7, 8,9,10,11, 12,13,14,15, 16,17,18,19, 20};
  const int wn[17]   = {16384,64,16384,64, 32768,512,512,512, 262144,512,512,512,
                        8192,16,16,16, 8192};
  for (int i = 0; i < 17; ++i) woff[i + 1] = woff[i] + wn[i];

  WSrc wsrc;
  int wtotal = 0;
  for (int i = 0; i < 17; ++i) {
    wsrc.p[i] = d_in[widx[i]]; wsrc.n[i] = wn[i];
    wsrc.dst[i] = wc + woff[i]; wsrc.M[i] = 0; wsrc.st[i] = 0;
    wtotal += wn[i];
  }
  // transposed destinations: src row-major [K][M] -> dst[m*st + k]
  wsrc.dst[0]  = fc0t;            wsrc.M[0]  = 64;  wsrc.st[0]  = 256; // fc0W
  wsrc.dst[2]  = fc1t;            wsrc.M[2]  = 64;  wsrc.st[2]  = 256; // fc1W
  wsrc.dst[4]  = W0t;             wsrc.M[4]  = 512; wsrc.st[4]  = 64;  // W0
  wsrc.dst[8]  = W1t;             wsrc.M[8]  = 512; wsrc.st[8]  = 512; // W1
  wsrc.dst[12] = W2c;             wsrc.M[12] = 16;  wsrc.st[12] = 512; // W2
  wsrc.dst[16] = W2c + 16 * 512;  wsrc.M[16] = 16;  wsrc.st[16] = 512; // resW2
  k_canon<<<blk(wtotal, B), B, 0, stream>>>(wsrc, flags, wtotal);
  k_convx<<<blk((long)NNODES * 32, B), B, 0, stream>>>(x0, x1, xb, flags);

  const bf16 *fc0b = wc + woff[1], *fc1b = wc + woff[3];
  const bf16 *al0  = wc + woff[5],  *ar0 = wc + woff[6],  *b0 = wc + woff[7];
  const bf16 *al1  = wc + woff[9],  *ar1 = wc + woff[10], *b1 = wc + woff[11];
  const bf16 *al2  = wc + woff[13], *ar2 = wc + woff[14], *b2 = wc + woff[15];

  // ---- CSR build: parallel scan (A: block sums, B: scan sums, C: scatter) ----
  k_bsum <<<NSCB, 1024, 0, stream>>>(deg, bsum, NNODES);
  k_bscan<<<1, 64, 0, stream>>>(bsum, row_start, NSCB, NNODES);
  k_scan2<<<NSCB, 1024, 0, stream>>>(deg, bsum, row_start, cursor, NNODES);
  k_fill<<<blk(NEDGES, B), B, 0, stream>>>(src32, dst32, cursor, csr_src, NEDGES);

  auto gemm = [&](const bf16* A, const bf16* Wt, bf16* C, int N, int K,
                  int ldc, int Mout, int ytiles, const bf16* bias,
                  const bf16* gal = nullptr, const bf16* gar = nullptr,
                  float* gel = nullptr, float* ger = nullptr,
                  unsigned* gM = nullptr) {
    dim3 g(blk(N, 128), ytiles);
    k_gemm_mfma<<<g, 256, 0, stream>>>(A, Wt, C, N, K, ldc, Mout, bias,
                                       gal, gar, gel, ger, gM);
  };

  // ---- input projections ----
  gemm(xb, fc0t, h0, NHALF, 256, 64, 64, 1, fc0b);
  gemm(xb + (size_t)NHALF * 256, fc1t, h0 + (size_t)NHALF * 64, NHALF, 256, 64, 64, 1, fc1b);

  unsigned aggGrid = blk((long)NNODES * 64, B);
  unsigned nblk1 = blk(NNODES, B);

  // ---- layer 0: 64 -> 8x64, ELU (el/er/max fused into GEMM epilogue) ----
  gemm(h0, W0t, ft, NNODES, 64, 512, 512, 4, nullptr, al0, ar0, el, er, Menc);
  k_agg8<<<aggGrid, B, 0, stream>>>(row_start, csr_src, el, er, Menc, ft, nullptr, b0,
                                    hB, nullptr, 0, flags, 0);

  // ---- layer 1: 512 -> 8x64, identity residual, ELU (+ encoded out) ----
  gemm(hB, W1t, ft, NNODES, 512, 512, 512, 4, nullptr, al1, ar1, el, er, Menc + 16);
  k_agg8<<<aggGrid, B, 0, stream>>>(row_start, csr_src, el, er, Menc + 16, ft, hB, b1,
                                    hB, d_out, (long)NNODES * 16, flags, 1);

  // ---- output layer: 512 -> 1x16 (+ fused resW2 in cols 16..31) ----
  gemm(hB, W2c, ft2, NNODES, 512, 32, 32, 1, nullptr);
  k_elr1<<<nblk1, B, 0, stream>>>(ft2, al2, ar2, el, er, Menc + 32);
  k_agg1<<<aggGrid, B, 0, stream>>>(row_start, csr_src, el, er, Menc + 32, ft2, b2, d_out, flags);
}